// Round 9
// baseline (412.295 us; speedup 1.0000x reference)
//
#include <hip/hip_runtime.h>
#include <float.h>
#include <math.h>

#define NB 2
#define MQ 16384
#define NQ (NB*MQ)          // 32768 queries
#define PP 5023
#define KNN 4
#define HPX 256
#define HWSZ (HPX*HPX)      // 65536
#define GD 12               // grid dim
#define GC (GD*GD*GD)       // 1728 cells
#define CAND_MAX 1024
#define SUM_SCALE 16384.f   // fixed-point scale for u64 sums atomics

// output layout (floats): densities[NQ], rgb[NQ*32], dist[NQ*4]
#define OUT_RGB_OFF  ((size_t)NQ)
#define OUT_DIST_OFF ((size_t)NQ + (size_t)NQ*32)

// workspace layout (bytes)
#define WS_SUMS_OFF   ((size_t)0x80000)
#define WS_PCNT_OFF   ((size_t)0x81000)
#define WS_PSTART_OFF ((size_t)0x85000)
#define WS_PCUR_OFF   ((size_t)0x89000)
#define WS_QCNT_OFF   ((size_t)0x8D000)
#define WS_QSTART_OFF ((size_t)0x91000)
#define WS_QCUR_OFF   ((size_t)0x95000)
#define WS_QID_OFF    ((size_t)0x99000)      // 32768*4 = 128 KB
#define WS_PG_OFF     ((size_t)0xC0000)      // 2*5023*16
#define WS_PID_OFF    ((size_t)0xF0000)      // 2*5023*4
#define WS_WP_OFF     ((size_t)0x100000)     // 29504 u32
#define WS_TEX_OFF    ((size_t)0x120000)     // 25.2 MB packed-f16 tex

// packed-weight sub-offsets (u32 units, in wp)
#define WP_PW1 0
#define WP_PW2 1920
#define WP_FW1 2944
#define WP_FW2 7040
#define WP_FW3 15232
#define WP_DW  23424
#define WP_RW1 23488
#define WP_RW2 28480

typedef __attribute__((ext_vector_type(2))) _Float16 half2v;

static __device__ __forceinline__ unsigned int pk2(float a, float b) {
    half2v h; h[0] = (_Float16)a; h[1] = (_Float16)b;   // RNE converts
    return __builtin_bit_cast(unsigned int, h);
}
static __device__ __forceinline__ float2 upk(unsigned int u) {
    half2v h = __builtin_bit_cast(half2v, u);
    return make_float2((float)h[0], (float)h[1]);
}
static __device__ __forceinline__ float dot2(unsigned int a, unsigned int b, float c) {
    return __builtin_amdgcn_fdot2(__builtin_bit_cast(half2v, a),
                                  __builtin_bit_cast(half2v, b), c, false);
}
static __device__ __forceinline__ int cell_of(float x) {
    int g = (int)(x * (float)GD);
    return (g < 0) ? 0 : ((g > GD-1) ? GD-1 : g);
}

// ------------------------------------------------------------------
// fused preprocessing: tex transpose (blocks 0..1535) | weight pack
// (blocks 1536..1791) | bucket count (blocks 1792..) — all independent.
struct FusedArgs {
    const float* src[8];
    int off[8]; int din[8]; int dout[8];
};
__global__ __launch_bounds__(256) void k_fused(
    FusedArgs a, unsigned int* __restrict__ wp,
    const float* __restrict__ tex, unsigned int* __restrict__ tex16,
    const float* __restrict__ pts, const float* __restrict__ coords,
    unsigned int* __restrict__ pcnt, unsigned int* __restrict__ qcnt,
    int use_t)
{
    const int b = blockIdx.x;
    const int tid = threadIdx.x;
    if (b < 1536) {
        // ---- texture transpose + f16 pack: [n3][32][HW] -> [n3][HW][16] u32
        if (!use_t) return;
        const int n3 = b >> 8;
        const int hw = ((b & 255) << 8) + tid;
        const float* s = tex + (size_t)n3 * 32 * HWSZ + hw;
        float v[32];
#pragma unroll
        for (int c = 0; c < 32; ++c) v[c] = s[(size_t)c * HWSZ];
        uint4* d = (uint4*)(tex16 + ((size_t)n3 * HWSZ + hw) * 16);
#pragma unroll
        for (int c = 0; c < 4; ++c)
            d[c] = make_uint4(pk2(v[8*c], v[8*c+1]), pk2(v[8*c+2], v[8*c+3]),
                              pk2(v[8*c+4], v[8*c+5]), pk2(v[8*c+6], v[8*c+7]));
    } else if (b < 1536 + 256) {
        // ---- weight pack
        const int b2 = b - 1536;
        const int mid = b2 >> 5;
        const int idx = (b2 & 31) * 256 + tid;
        const int DIN = a.din[mid], DOUT = a.dout[mid];
        const int din2 = (DIN + 1) >> 1;
        if (idx >= din2 * DOUT) return;
        const int i2 = idx / DOUT, j = idx - i2 * DOUT;
        const float* s = a.src[mid];
        const float lo = s[(2*i2) * DOUT + j];
        const float hi = (2*i2 + 1 < DIN) ? s[(2*i2 + 1) * DOUT + j] : 0.f;
        wp[a.off[mid] + idx] = pk2(lo, hi);
    } else {
        // ---- bucket count: points then queries
        const int i = (b - 1792) * 256 + tid;
        if (i < NB * PP) {
            const int n = (i >= PP) ? 1 : 0;
            const float px = pts[3*i], py = pts[3*i+1], pz = pts[3*i+2];
            const int c = (cell_of(pz)*GD + cell_of(py))*GD + cell_of(px);
            atomicAdd(&pcnt[n*GC + c], 1u);
        } else if (i - NB*PP < NQ) {
            const int q = i - NB*PP;
            const int n = q >> 14;
            const float cx = coords[3*q], cy = coords[3*q+1], cz = coords[3*q+2];
            const int c = (cell_of(cz)*GD + cell_of(cy))*GD + cell_of(cx);
            atomicAdd(&qcnt[n*GC + c], 1u);
        }
    }
}

// ------------------------------------------------------------------
// scan via wave shuffles: 8 barriers total (was ~120 with Hillis-Steele).
__global__ __launch_bounds__(1024) void k_scan2(const unsigned int* __restrict__ pcnt,
                                                unsigned int* __restrict__ psta,
                                                unsigned int* __restrict__ pcur,
                                                const unsigned int* __restrict__ qcnt,
                                                unsigned int* __restrict__ qsta,
                                                unsigned int* __restrict__ qcur) {
    __shared__ unsigned int wsum[16];
    const int t = threadIdx.x;
    const int lane = t & 63, wv = t >> 6;
#pragma unroll 1
    for (int which = 0; which < 2; ++which) {
        const unsigned int* cnt = which ? qcnt : pcnt;
        unsigned int* start  = which ? qsta : psta;
        unsigned int* cursor = which ? qcur : pcur;
        const int stride = which ? MQ : PP;
#pragma unroll 1
        for (int n = 0; n < 2; ++n) {
            const unsigned int* c = cnt + n*GC;
            unsigned int a = (2*t   < GC) ? c[2*t]   : 0u;
            unsigned int b = (2*t+1 < GC) ? c[2*t+1] : 0u;
            unsigned int s = a + b;
            // intra-wave inclusive scan (no barriers)
            unsigned int inc = s;
#pragma unroll
            for (int off = 1; off < 64; off <<= 1) {
                unsigned int v = __shfl_up(inc, off);
                if (lane >= off) inc += v;
            }
            if (lane == 63) wsum[wv] = inc;
            __syncthreads();
            // wave 0 turns the 16 wave totals into exclusive bases
            if (wv == 0) {
                unsigned int x = (lane < 16) ? wsum[lane] : 0u;
                unsigned int xin = x;
#pragma unroll
                for (int off = 1; off < 16; off <<= 1) {
                    unsigned int v = __shfl_up(xin, off);
                    if (lane >= off) xin += v;
                }
                if (lane < 16) wsum[lane] = xin - x;   // exclusive wave base
            }
            __syncthreads();
            const unsigned int excl = wsum[wv] + (inc - s);
            const unsigned int base = n * stride;
            if (2*t < GC)   { start[n*GC + 2*t]   = base + excl;
                              cursor[n*GC + 2*t]  = base + excl; }
            if (2*t+1 < GC) { start[n*GC + 2*t+1] = base + excl + a;
                              cursor[n*GC + 2*t+1]= base + excl + a; }
            __syncthreads();   // wsum reused next round
        }
    }
}

__global__ __launch_bounds__(256) void k_scatter(const float* __restrict__ pts,
                                                 const float* __restrict__ coords,
                                                 unsigned int* __restrict__ pcur,
                                                 unsigned int* __restrict__ qcur,
                                                 float4* __restrict__ pg,
                                                 int* __restrict__ pid,
                                                 int* __restrict__ qid) {
    const int i = blockIdx.x * 256 + threadIdx.x;
    if (i < NB * PP) {
        const int n = (i >= PP) ? 1 : 0;
        const int local = i - n * PP;
        const float px = pts[3*i], py = pts[3*i+1], pz = pts[3*i+2];
        const int c = (cell_of(pz)*GD + cell_of(py))*GD + cell_of(px);
        const unsigned int pos = atomicAdd(&pcur[n*GC + c], 1u);
        pg[pos] = make_float4(px, py, pz, fmaf(px, px, fmaf(py, py, pz*pz)));
        pid[pos] = local;
    } else if (i - NB*PP < NQ) {
        const int q = i - NB*PP;
        const int n = q >> 14;
        const float cx = coords[3*q], cy = coords[3*q+1], cz = coords[3*q+2];
        const int c = (cell_of(cz)*GD + cell_of(cy))*GD + cell_of(cx);
        const unsigned int pos = atomicAdd(&qcur[n*GC + c], 1u);
        qid[pos] = q;
    }
}

// ------------------------------------------------------------------
// KNN (proven R13) + per-block inverse-distance sums via ONE set of native
// u64 fixed-point atomics per block (NOT the R5 float-CAS-per-query mistake).
__global__ __launch_bounds__(256) void k_knn_cell(
    const float* __restrict__ coords,
    const unsigned int* __restrict__ pstart, const unsigned int* __restrict__ pcnt,
    const float4* __restrict__ pg, const int* __restrict__ pid,
    const unsigned int* __restrict__ qstart, const unsigned int* __restrict__ qcnt,
    const int* __restrict__ qid,
    float* __restrict__ odist, int* __restrict__ oidx,
    unsigned long long* __restrict__ sums64)
{
    __shared__ float4 cand[CAND_MAX];        // 16 KB
    __shared__ int    cidx[CAND_MAX];        // 4 KB
    __shared__ unsigned int rs[25], ro[26];
    const int tid = threadIdx.x;
    const int bid = blockIdx.x;              // 2*GC
    const int n = bid / GC, c = bid % GC;
    const unsigned int qn = qcnt[n*GC + c];
    if (qn == 0) return;
    const int gz = c / (GD*GD), gy = (c / GD) % GD, gx = c % GD;

    const int x0 = max(gx-2,0), x1 = min(gx+2,GD-1);
    const int y0 = max(gy-2,0), y1 = min(gy+2,GD-1), ny = y1-y0+1;
    const int z0 = max(gz-2,0), z1 = min(gz+2,GD-1), nz = z1-z0+1;
    const int nrow = ny*nz;                  // <= 25

    __shared__ unsigned int rcnt[25];
    if (tid < nrow) {
        const int yy = y0 + tid % ny;
        const int zz = z0 + tid / ny;
        const int c0 = n*GC + (zz*GD + yy)*GD + x0;
        const int c1 = n*GC + (zz*GD + yy)*GD + x1;
        const unsigned int s = pstart[c0];
        rs[tid]   = s;
        rcnt[tid] = (pstart[c1] + pcnt[c1]) - s;   // x-contiguous range
    }
    __syncthreads();
    if (tid == 0) {
        unsigned int acc = 0; ro[0] = 0;
        for (int t = 0; t < nrow; ++t) { acc += rcnt[t]; ro[t+1] = acc; }
    }
    __syncthreads();
    const unsigned int total = ro[nrow];
    const bool ovf = (total > CAND_MAX);
    if (!ovf) {
        for (unsigned int i = tid; i < total; i += 256) {
            int lo = 0, hi = nrow;
            while (hi - lo > 1) { int mid = (lo + hi) >> 1; if (ro[mid] <= i) lo = mid; else hi = mid; }
            const unsigned int src = rs[lo] + (i - ro[lo]);
            cand[i] = pg[src];
            cidx[i] = pid[src];
        }
    }
    __syncthreads();

    const float w = 1.0f / (float)GD;
    const float thresh = 4.f * w * w * 0.999f;
    const int grp = tid >> 4, l16 = tid & 15;
    const unsigned int qs = qstart[n*GC + c];
    float sA0 = 0.f, sA1 = 0.f, sA2 = 0.f, sA3 = 0.f;   // per-thread 1/d sums

#define INS4(d, i) { \
        bool L3 = ((d) < bd3) || ((d) == bd3 && (i) < bi3); \
        bool L2 = ((d) < bd2) || ((d) == bd2 && (i) < bi2); \
        bool L1 = ((d) < bd1) || ((d) == bd1 && (i) < bi1); \
        bool L0 = ((d) < bd0) || ((d) == bd0 && (i) < bi0); \
        bd3 = L3 ? (L2 ? bd2 : (d)) : bd3;  bi3 = L3 ? (L2 ? bi2 : (i)) : bi3; \
        bd2 = L2 ? (L1 ? bd1 : (d)) : bd2;  bi2 = L2 ? (L1 ? bi1 : (i)) : bi2; \
        bd1 = L1 ? (L0 ? bd0 : (d)) : bd1;  bi1 = L1 ? (L0 ? bi0 : (i)) : bi1; \
        bd0 = L0 ? (d) : bd0;               bi0 = L0 ? (i) : bi0; }

#define MERGE16() { \
        float bd[4] = { bd0, bd1, bd2, bd3 }; \
        int   bi[4] = { bi0, bi1, bi2, bi3 }; \
        for (int mask = 1; mask < 16; mask <<= 1) { \
            float od[4]; int oi[4]; \
            for (int j = 0; j < 4; ++j) { od[j] = __shfl_xor(bd[j], mask); \
                                          oi[j] = __shfl_xor(bi[j], mask); } \
            float e[4]; int ei[4]; \
            for (int j = 0; j < 4; ++j) { \
                float ad = bd[j], xd = od[3-j]; \
                int   ai = bi[j], xi = oi[3-j]; \
                bool ta = (ad < xd) || (ad == xd && ai < xi); \
                e[j] = ta ? ad : xd; ei[j] = ta ? ai : xi; \
            } \
            { bool sw = (e[2] < e[0]) || (e[2] == e[0] && ei[2] < ei[0]); \
              if (sw) { float td=e[0]; e[0]=e[2]; e[2]=td; int ti=ei[0]; ei[0]=ei[2]; ei[2]=ti; } } \
            { bool sw = (e[3] < e[1]) || (e[3] == e[1] && ei[3] < ei[1]); \
              if (sw) { float td=e[1]; e[1]=e[3]; e[3]=td; int ti=ei[1]; ei[1]=ei[3]; ei[3]=ti; } } \
            { bool sw = (e[1] < e[0]) || (e[1] == e[0] && ei[1] < ei[0]); \
              if (sw) { float td=e[0]; e[0]=e[1]; e[1]=td; int ti=ei[0]; ei[0]=ei[1]; ei[1]=ti; } } \
            { bool sw = (e[3] < e[2]) || (e[3] == e[2] && ei[3] < ei[2]); \
              if (sw) { float td=e[2]; e[2]=e[3]; e[3]=td; int ti=ei[2]; ei[2]=ei[3]; ei[3]=ti; } } \
            for (int j = 0; j < 4; ++j) { bd[j] = e[j]; bi[j] = ei[j]; } \
        } \
        bd0 = bd[0]; bd1 = bd[1]; bd2 = bd[2]; bd3 = bd[3]; \
        bi0 = bi[0]; bi1 = bi[1]; bi2 = bi[2]; bi3 = bi[3]; }

#pragma unroll 1
    for (unsigned int qb = 0; qb < qn; qb += 16) {
        const unsigned int qi = qb + grp;
        if (qi >= qn) continue;
        const int q = qid[qs + qi];
        const float cx = coords[3*q], cy = coords[3*q+1], cz = coords[3*q+2];
        const float ccq = fmaf(cx, cx, fmaf(cy, cy, cz*cz));

        float bd0 = FLT_MAX, bd1 = FLT_MAX, bd2 = FLT_MAX, bd3 = FLT_MAX;
        int   bi0 = 0x7fffffff, bi1 = 0x7fffffff, bi2 = 0x7fffffff, bi3 = 0x7fffffff;

        if (!ovf) {
#pragma unroll 1
            for (unsigned int j = l16; j < total; j += 16) {
                const float4 P = cand[j];
                const int i = cidx[j];
                const float dt = fmaf(cx, P.x, fmaf(cy, P.y, cz * P.z));
                const float d = fmaf(-2.0f, dt, ccq + P.w);
                INS4(d, i)
            }
            MERGE16()
        }
        if (ovf || !(bd3 < thresh)) {
            bd0 = bd1 = bd2 = bd3 = FLT_MAX;
            bi0 = bi1 = bi2 = bi3 = 0x7fffffff;
#pragma unroll 1
            for (int j = l16; j < PP; j += 16) {
                const float4 P = pg[n*PP + j];
                const int i = pid[n*PP + j];
                const float dt = fmaf(cx, P.x, fmaf(cy, P.y, cz * P.z));
                const float d = fmaf(-2.0f, dt, ccq + P.w);
                INS4(d, i)
            }
            MERGE16()
        }
        if (l16 == 0) {
            *(float4*)(odist + (size_t)q*4) = make_float4(bd0, bd1, bd2, bd3);
            *(int4*)(oidx + (size_t)q*4)    = make_int4(bi0, bi1, bi2, bi3);
            sA0 += 1.0f / bd0;  sA1 += 1.0f / bd1;
            sA2 += 1.0f / bd2;  sA3 += 1.0f / bd3;
        }
    }
#undef INS4
#undef MERGE16

    // block-reduce the 16 l16==0 partials; 4 native u64 atomics per block
    __syncthreads();
    {
        float4* red = cand;                  // reuse staged-candidate LDS
        if (l16 == 0) red[tid >> 4] = make_float4(sA0, sA1, sA2, sA3);
        __syncthreads();
        if (tid == 0) {
            float s0 = 0.f, s1 = 0.f, s2 = 0.f, s3 = 0.f;
            for (int i = 0; i < 16; ++i) {
                const float4 v = red[i];
                s0 += v.x; s1 += v.y; s2 += v.z; s3 += v.w;
            }
            atomicAdd(&sums64[n*4 + 0], (unsigned long long)(s0 * SUM_SCALE + 0.5f));
            atomicAdd(&sums64[n*4 + 1], (unsigned long long)(s1 * SUM_SCALE + 0.5f));
            atomicAdd(&sums64[n*4 + 2], (unsigned long long)(s2 * SUM_SCALE + 0.5f));
            atomicAdd(&sums64[n*4 + 3], (unsigned long long)(s3 * SUM_SCALE + 0.5f));
        }
    }
}

// ------------------------------------------------------------------
static __device__ __forceinline__ float harm_val(int h, float rx, float ry, float rz) {
    if (h >= 27) return 0.f;
    float v;
    if (h < 24) {
        int base = (h < 12) ? h : (h - 12);
        float rv = (base >> 2) == 0 ? rx : ((base >> 2) == 1 ? ry : rz);
        float e = rv * (float)(1 << (base & 3));
        v = (h < 12) ? sinf(e) : cosf(e);
    } else {
        v = (h == 24) ? rx : ((h == 25) ? ry : rz);
    }
    return v;
}

#define SW 128   // S row stride in u32 (128 queries per block)

// gemv, 2 queries/lane: act b64 from S (pair 2*lane), weights b128 from W (LDS).
template<int DIN2, int DOUT, int TILE>
__device__ __forceinline__ void gemv2(const unsigned int* Xp, int lane,
                                      const unsigned int* Wl,
                                      const float* __restrict__ bias, int j0,
                                      float (&aa)[TILE], float (&ab)[TILE]) {
    static_assert(TILE % 4 == 0, "");
#pragma unroll
    for (int u = 0; u < TILE; ++u) { aa[u] = bias[j0 + u]; ab[u] = aa[u]; }
#pragma unroll
    for (int i2 = 0; i2 < DIN2; ++i2) {
        const uint2 xv = *(const uint2*)(Xp + i2 * SW + 2*lane);
        const uint4* wr = (const uint4*)(Wl + i2 * DOUT + j0);
#pragma unroll
        for (int t = 0; t < TILE/4; ++t) {
            const uint4 w4 = wr[t];
            aa[4*t+0] = dot2(xv.x, w4.x, aa[4*t+0]);  ab[4*t+0] = dot2(xv.y, w4.x, ab[4*t+0]);
            aa[4*t+1] = dot2(xv.x, w4.y, aa[4*t+1]);  ab[4*t+1] = dot2(xv.y, w4.y, ab[4*t+1]);
            aa[4*t+2] = dot2(xv.x, w4.z, aa[4*t+2]);  ab[4*t+2] = dot2(xv.y, w4.z, ab[4*t+2]);
            aa[4*t+3] = dot2(xv.x, w4.w, aa[4*t+3]);  ab[4*t+3] = dot2(xv.y, w4.w, ab[4*t+3]);
        }
    }
}

// ------------------------------------------------------------------
// main v23 == v22 k_main (proven 92.4 µs) except sums read as u64 fixed-point.
__global__ __launch_bounds__(1024, 1) void k_main(
    const float* __restrict__ coords, const float* __restrict__ dirs,
    const float* __restrict__ pts, const float* __restrict__ tex_raw,
    const unsigned int* __restrict__ tex16, const float* __restrict__ emb,
    const unsigned int* __restrict__ wp,
    const float* __restrict__ pb1, const float* __restrict__ pb2,
    const float* __restrict__ fb1, const float* __restrict__ fb2,
    const float* __restrict__ fb3, const float* __restrict__ db,
    const float* __restrict__ rb1, const float* __restrict__ rb2,
    const int* __restrict__ idxbuf, const float* __restrict__ distbuf,
    const unsigned long long* __restrict__ sums64, float* __restrict__ out,
    int use_tex_t)
{
    __shared__ unsigned int S[128 * SW];               // 64 KB
    __shared__ __align__(16) unsigned int W[16384];    // 64 KB
    __shared__ float Rstg[128 * 33];                   // 16.5 KB
    const int tid  = threadIdx.x;
    const int lane = tid & 63;
    const int wv   = __builtin_amdgcn_readfirstlane(tid >> 6);   // 0..15
    const int q0   = blockIdx.x * 128;                 // 256 blocks
    const int n    = q0 >> 14;
    const int qa   = q0 + 2*lane;

#define STAGE(dstu4, srcoff, len) { \
        const uint4* s4_ = (const uint4*)(wp + (srcoff)); \
        for (int i_ = tid; i_ < (len)/4; i_ += 1024) ((uint4*)W)[(dstu4) + i_] = s4_[i_]; }

    // A-gather: neighbor features (emb, waves 0..7) + rel-harmonics
    // (waves 8..14) for neighbor kk -> S rows 64..93.
    auto gatherA = [&](int kk) {
#pragma unroll
        for (int s = 0; s < 2; ++s) {
            const int q = qa + s;
            const int id = idxbuf[(size_t)q*4 + kk];
            if (wv < 8) {
                const float4 e = *(const float4*)(emb + (size_t)id * 32 + wv*4);
                S[(64 + 2*wv    )*SW + 2*lane + s] = pk2(e.x, e.y);
                S[(64 + 2*wv + 1)*SW + 2*lane + s] = pk2(e.z, e.w);
            } else {
                const int w8 = wv - 8;
                if (w8 < 7) {
                    const float cx = coords[q*3+0], cy = coords[q*3+1], cz = coords[q*3+2];
                    const float nx = pts[((size_t)n*PP + id)*3 + 0];
                    const float ny = pts[((size_t)n*PP + id)*3 + 1];
                    const float nz = pts[((size_t)n*PP + id)*3 + 2];
                    float rx = cx - nx, ry = cy - ny, rz = cz - nz;
                    float nrm = sqrtf(fmaf(rx, rx, fmaf(ry, ry, rz*rz)));
                    float inv = 1.f / fmaxf(nrm, 1e-12f);
                    rx *= inv; ry *= inv; rz *= inv;
#pragma unroll
                    for (int t = 0; t < 2; ++t) {
                        const int pr = 2*w8 + t;          // 0..13
                        S[(80 + pr)*SW + 2*lane + s] =
                            pk2(harm_val(2*pr, rx, ry, rz), harm_val(2*pr + 1, rx, ry, rz));
                    }
                }
            }
        }
    };

    // ---------- tex sampling: wave = ch-pair g, lane = query pair ----------
    unsigned int tex_pack[2];
    {
        const int g = wv;
#pragma unroll
        for (int s = 0; s < 2; ++s) {
            const int q = qa + s;
            const float cx = coords[q*3+0], cy = coords[q*3+1], cz = coords[q*3+2];
            float a0 = 0.f, a1 = 0.f;
#pragma unroll
            for (int pl = 0; pl < 3; ++pl) {
                float gx = (pl == 2) ? cz : cx;
                float gy = (pl == 0) ? cy : ((pl == 1) ? cz : cx);
                float x = (gx + 1.f) * 128.f - 0.5f;
                float y = (gy + 1.f) * 128.f - 0.5f;
                float x0f = floorf(x), y0f = floorf(y);
                float wx1 = x - x0f, wy1 = y - y0f;
                float wx0 = 1.f - wx1, wy0 = 1.f - wy1;
                int x0 = (int)x0f, y0 = (int)y0f;
                int n3 = n * 3 + pl;
                int  xs[4] = { x0, x0+1, x0,   x0+1 };
                int  ys[4] = { y0, y0,   y0+1, y0+1 };
                float wt[4] = { wx0*wy0, wx1*wy0, wx0*wy1, wx1*wy1 };
#pragma unroll
                for (int c = 0; c < 4; ++c) {
                    int xi = xs[c], yi = ys[c];
                    if (xi >= 0 && xi < HPX && yi >= 0 && yi < HPX) {
                        float wgt = wt[c];
                        if (use_tex_t) {
                            const unsigned int v = tex16[
                                ((size_t)n3 * HWSZ + (size_t)yi * HPX + xi) * 16 + g];
                            const float2 f = upk(v);
                            a0 = fmaf(wgt, f.x, a0);
                            a1 = fmaf(wgt, f.y, a1);
                        } else {
                            size_t base = ((size_t)(n3 * 32 + g * 2)) * HWSZ + (size_t)yi * HPX + xi;
                            a0 = fmaf(wgt, tex_raw[base], a0);
                            a1 = fmaf(wgt, tex_raw[base + HWSZ], a1);
                        }
                    }
                }
            }
            tex_pack[s] = pk2(a0 * (1.f/3.f), a1 * (1.f/3.f));
        }
    }

    STAGE(0,    WP_PW1, 1920)        // pw1 @ u32 0
    STAGE(512,  WP_PW2, 1024)        // pw2 @ u32 2048
    STAGE(1024, WP_FW1, 4096)        // fw1 @ u32 4096
    gatherA(0);                      // A_0 hoisted before first barrier
    __syncthreads();

    STAGE(2048, WP_FW2, 8192)        // fw2 @ u32 8192, hidden under B_0's phase

    // ---------- neighbor loop: B_k; sync; {C_k + A_{k+1} | feat}; sync ----------
#pragma unroll 1
    for (int k = 0; k < KNN; ++k) {
        // B_k: p1 59->64 relu (W@0) -> h1 rows 96..127
        {
            float aa[4], ab[4];
            gemv2<30, 64, 4>(S + 64*SW, lane, W, pb1, wv * 4, aa, ab);
            S[(96 + 2*wv    )*SW + 2*lane + 0] = pk2(fmaxf(aa[0], 0.f), fmaxf(aa[1], 0.f));
            S[(96 + 2*wv    )*SW + 2*lane + 1] = pk2(fmaxf(ab[0], 0.f), fmaxf(ab[1], 0.f));
            S[(96 + 2*wv + 1)*SW + 2*lane + 0] = pk2(fmaxf(aa[2], 0.f), fmaxf(aa[3], 0.f));
            S[(96 + 2*wv + 1)*SW + 2*lane + 1] = pk2(fmaxf(ab[2], 0.f), fmaxf(ab[3], 0.f));
        }
        __syncthreads();
        // C_k: p2 64->32 (W@2048), wk-scaled -> row k*16 + wv
        {
            float aa[2], ab[2];
            aa[0] = pb2[wv*2 + 0]; aa[1] = pb2[wv*2 + 1];
            ab[0] = aa[0]; ab[1] = aa[1];
#pragma unroll
            for (int i2 = 0; i2 < 32; ++i2) {
                const uint2 xv = *(const uint2*)(S + (96 + i2)*SW + 2*lane);
                const unsigned int w0 = W[2048 + i2*32 + wv*2 + 0];
                const unsigned int w1 = W[2048 + i2*32 + wv*2 + 1];
                aa[0] = dot2(xv.x, w0, aa[0]);  ab[0] = dot2(xv.y, w0, ab[0]);
                aa[1] = dot2(xv.x, w1, aa[1]);  ab[1] = dot2(xv.y, w1, ab[1]);
            }
            const float fsum = (float)sums64[n*4 + k] * (1.f / SUM_SCALE);
            const float da  = distbuf[(size_t)qa*4 + k];
            const float dbq = distbuf[(size_t)(qa+1)*4 + k];
            const float wka = (1.0f / da)  / fsum;
            const float wkb = (1.0f / dbq) / fsum;
            S[(k*16 + wv)*SW + 2*lane + 0] = pk2(wka * aa[0], wka * aa[1]);
            S[(k*16 + wv)*SW + 2*lane + 1] = pk2(wkb * ab[0], wkb * ab[1]);
        }
        if (k < KNN-1) {
            gatherA(k+1);              // rows 64..93, disjoint from C_k
        } else {
            // feat -> rows 64..95. pts-feat reads this thread's OWN C_k rows
            // (same row k*16+wv, same cols 2*lane) — same-thread LDS, no
            // barrier needed for the k=3 value written just above.
            S[(64 + wv)*SW + 2*lane + 0] = tex_pack[0];
            S[(64 + wv)*SW + 2*lane + 1] = tex_pack[1];
#pragma unroll
            for (int s = 0; s < 2; ++s) {
                float a = 0.f, b = 0.f;
#pragma unroll
                for (int kk = 0; kk < 4; ++kk) {
                    float2 v = upk(S[(kk*16 + wv)*SW + 2*lane + s]);
                    a += v.x; b += v.y;
                }
                S[(80 + wv)*SW + 2*lane + s] = pk2(a, b);
            }
        }
        __syncthreads();
    }

    // ---------- E: fw1 (W@4096) 64->128 relu, rows 64..95 -> rows 0..63 ----------
    {
        float aa[8], ab[8];
        gemv2<32, 128, 8>(S + 64*SW, lane, W + 4096, fb1, wv * 8, aa, ab);
#pragma unroll
        for (int u = 0; u < 4; ++u) {
            S[(4*wv + u)*SW + 2*lane + 0] = pk2(fmaxf(aa[2*u], 0.f), fmaxf(aa[2*u+1], 0.f));
            S[(4*wv + u)*SW + 2*lane + 1] = pk2(fmaxf(ab[2*u], 0.f), fmaxf(ab[2*u+1], 0.f));
        }
    }
    __syncthreads();
    // ---------- F: fw2 (W@8192) 128->128 relu, rows 0..63 -> 64..127;
    //             + stage fw3 -> W@0 (pw1/pw2/fw1 dead) ----------
    {
        float aa[8], ab[8];
        gemv2<64, 128, 8>(S, lane, W + 8192, fb2, wv * 8, aa, ab);
#pragma unroll
        for (int u = 0; u < 4; ++u) {
            S[(64 + 4*wv + u)*SW + 2*lane + 0] = pk2(fmaxf(aa[2*u], 0.f), fmaxf(aa[2*u+1], 0.f));
            S[(64 + 4*wv + u)*SW + 2*lane + 1] = pk2(fmaxf(ab[2*u], 0.f), fmaxf(ab[2*u+1], 0.f));
        }
    }
    STAGE(0, WP_FW3, 8192)
    __syncthreads();
    // ---------- G: fw3 (W@0) 128->128, rows 64..127 -> rows 0..63;
    //             + stage rw1/rw2/dw -> W@8192.. (fw2 dead) ----------
    {
        float aa[8], ab[8];
        gemv2<64, 128, 8>(S + 64*SW, lane, W, fb3, wv * 8, aa, ab);
#pragma unroll
        for (int u = 0; u < 4; ++u) {
            S[(4*wv + u)*SW + 2*lane + 0] = pk2(aa[2*u], aa[2*u+1]);
            S[(4*wv + u)*SW + 2*lane + 1] = pk2(ab[2*u], ab[2*u+1]);
        }
    }
    STAGE(2048, WP_RW1, 4992)        // rw1 @ u32 8192
    STAGE(3296, WP_RW2, 1024)        // rw2 @ u32 13184
    STAGE(3552, WP_DW, 64)           // dw  @ u32 14208
    __syncthreads();
    // ---------- ray-harm rows 64..77 (rows 64..127 dead after G) ----------
    if (wv < 14) {
#pragma unroll
        for (int s = 0; s < 2; ++s) {
            const int q = qa + s;
            float dx = dirs[q*3+0], dy = dirs[q*3+1], dz = dirs[q*3+2];
            float dn = sqrtf(fmaf(dx, dx, fmaf(dy, dy, dz*dz)));
            float inv = 1.f / fmaxf(dn, 1e-12f);
            dx *= inv; dy *= inv; dz *= inv;
            S[(64 + wv)*SW + 2*lane + s] = pk2(harm_val(2*wv, dx, dy, dz),
                                               harm_val(2*wv + 1, dx, dy, dz));
        }
    }
    __syncthreads();
    // ---------- I: rw1 (W@8192) 155->64 relu; rows 0..77 -> rows 78..109 ----------
    {
        float aa[4], ab[4];
        gemv2<78, 64, 4>(S, lane, W + 8192, rb1, wv * 4, aa, ab);
        S[(78 + 2*wv    )*SW + 2*lane + 0] = pk2(fmaxf(aa[0], 0.f), fmaxf(aa[1], 0.f));
        S[(78 + 2*wv    )*SW + 2*lane + 1] = pk2(fmaxf(ab[0], 0.f), fmaxf(ab[1], 0.f));
        S[(78 + 2*wv + 1)*SW + 2*lane + 0] = pk2(fmaxf(aa[2], 0.f), fmaxf(aa[3], 0.f));
        S[(78 + 2*wv + 1)*SW + 2*lane + 1] = pk2(fmaxf(ab[2], 0.f), fmaxf(ab[3], 0.f));
    }
    __syncthreads();
    // ---------- J: rw2 (W@13184) 64->32 + sigmoid -> Rstg; density (wave 15,
    //             dw @ W@14208) ----------
    {
        float aa[2], ab[2];
        aa[0] = rb2[wv*2 + 0]; aa[1] = rb2[wv*2 + 1];
        ab[0] = aa[0]; ab[1] = aa[1];
#pragma unroll
        for (int i2 = 0; i2 < 32; ++i2) {
            const uint2 xv = *(const uint2*)(S + (78 + i2)*SW + 2*lane);
            const unsigned int w0 = W[13184 + i2*32 + wv*2 + 0];
            const unsigned int w1 = W[13184 + i2*32 + wv*2 + 1];
            aa[0] = dot2(xv.x, w0, aa[0]);  ab[0] = dot2(xv.y, w0, ab[0]);
            aa[1] = dot2(xv.x, w1, aa[1]);  ab[1] = dot2(xv.y, w1, ab[1]);
        }
#pragma unroll
        for (int u = 0; u < 2; ++u) {
            const int j = wv*2 + u;
            float va = (u == 0) ? aa[0] : aa[1];
            float vb = (u == 0) ? ab[0] : ab[1];
            if (j < 3) {
                va = 1.002f * (1.f / (1.f + expf(-va))) - 0.001f;
                vb = 1.002f * (1.f / (1.f + expf(-vb))) - 0.001f;
            }
            Rstg[(2*lane    ) * 33 + j] = va;
            Rstg[(2*lane + 1) * 33 + j] = vb;
        }
        if (wv == 15) {
            float za = db[0], zb = db[0];
#pragma unroll 8
            for (int i2 = 0; i2 < 64; ++i2) {
                const uint2 xv = *(const uint2*)(S + i2*SW + 2*lane);
                const unsigned int wz = W[14208 + i2];
                za = dot2(xv.x, wz, za);
                zb = dot2(xv.y, wz, zb);
            }
#pragma unroll
            for (int s = 0; s < 2; ++s) {
                const int q = qa + s;
                const float z = (s == 0) ? za : zb;
                const float cx = coords[q*3+0], cy = coords[q*3+1], cz = coords[q*3+2];
                float selv = (cx > -1.f && cx < 1.f && cy > -1.f && cy < 1.f &&
                              cz > -1.f && cz < 1.f) ? 1.f : 0.f;
                float t10 = 10.f * z;
                float sp = (t10 > 20.f) ? t10 : log1pf(expf(t10));
                float raw = sp * 0.1f * selv;
                out[q] = 1.f - expf(-raw);
            }
        }
    }
    __syncthreads();
    // ---------- coalesced rgb writeback: 1 float4/thread ----------
    {
        const int cq = tid >> 3;             // 0..127
        const int j0 = (tid & 7) * 4;        // 0,4,...,28
        float4 v;
        v.x = Rstg[cq*33 + j0 + 0];
        v.y = Rstg[cq*33 + j0 + 1];
        v.z = Rstg[cq*33 + j0 + 2];
        v.w = Rstg[cq*33 + j0 + 3];
        *(float4*)(out + OUT_RGB_OFF + ((size_t)(q0 + cq))*32 + j0) = v;
    }
#undef STAGE
}

// ------------------------------------------------------------------
extern "C" void kernel_launch(void* const* d_in, const int* in_sizes, int n_in,
                              void* d_out, int out_size, void* d_ws, size_t ws_size,
                              hipStream_t stream) {
    (void)in_sizes; (void)n_in; (void)out_size;
    const float* coords = (const float*)d_in[0];
    const float* dirs   = (const float*)d_in[1];
    const float* pts    = (const float*)d_in[2];
    const float* tex    = (const float*)d_in[3];
    const float* emb    = (const float*)d_in[4];
    const float* pw1 = (const float*)d_in[5];  const float* pb1 = (const float*)d_in[6];
    const float* pw2 = (const float*)d_in[7];  const float* pb2 = (const float*)d_in[8];
    const float* fw1 = (const float*)d_in[9];  const float* fb1 = (const float*)d_in[10];
    const float* fw2 = (const float*)d_in[11]; const float* fb2 = (const float*)d_in[12];
    const float* fw3 = (const float*)d_in[13]; const float* fb3 = (const float*)d_in[14];
    const float* dw  = (const float*)d_in[15]; const float* db  = (const float*)d_in[16];
    const float* rw1 = (const float*)d_in[17]; const float* rb1 = (const float*)d_in[18];
    const float* rw2 = (const float*)d_in[19]; const float* rb2 = (const float*)d_in[20];

    float*        out     = (float*)d_out;
    int*          wsidx   = (int*)d_ws;
    unsigned long long* wssums64 = (unsigned long long*)((char*)d_ws + WS_SUMS_OFF);
    unsigned int* wspcnt  = (unsigned int*)((char*)d_ws + WS_PCNT_OFF);
    unsigned int* wspsta  = (unsigned int*)((char*)d_ws + WS_PSTART_OFF);
    unsigned int* wspcur  = (unsigned int*)((char*)d_ws + WS_PCUR_OFF);
    unsigned int* wsqcnt  = (unsigned int*)((char*)d_ws + WS_QCNT_OFF);
    unsigned int* wsqsta  = (unsigned int*)((char*)d_ws + WS_QSTART_OFF);
    unsigned int* wsqcur  = (unsigned int*)((char*)d_ws + WS_QCUR_OFF);
    int*          wsqid   = (int*)((char*)d_ws + WS_QID_OFF);
    float4*       wspg    = (float4*)((char*)d_ws + WS_PG_OFF);
    int*          wspid   = (int*)((char*)d_ws + WS_PID_OFF);
    unsigned int* wswp    = (unsigned int*)((char*)d_ws + WS_WP_OFF);
    unsigned int* wstex   = (unsigned int*)((char*)d_ws + WS_TEX_OFF);

    const size_t need_tex = WS_TEX_OFF + (size_t)6 * HWSZ * 16 * 4;
    const int use_t = (ws_size >= need_tex) ? 1 : 0;

    FusedArgs fa;
    fa.src[0] = pw1; fa.off[0] = WP_PW1; fa.din[0] = 59;  fa.dout[0] = 64;
    fa.src[1] = pw2; fa.off[1] = WP_PW2; fa.din[1] = 64;  fa.dout[1] = 32;
    fa.src[2] = fw1; fa.off[2] = WP_FW1; fa.din[2] = 64;  fa.dout[2] = 128;
    fa.src[3] = fw2; fa.off[3] = WP_FW2; fa.din[3] = 128; fa.dout[3] = 128;
    fa.src[4] = fw3; fa.off[4] = WP_FW3; fa.din[4] = 128; fa.dout[4] = 128;
    fa.src[5] = dw;  fa.off[5] = WP_DW;  fa.din[5] = 128; fa.dout[5] = 1;
    fa.src[6] = rw1; fa.off[6] = WP_RW1; fa.din[6] = 155; fa.dout[6] = 64;
    fa.src[7] = rw2; fa.off[7] = WP_RW2; fa.din[7] = 64;  fa.dout[7] = 32;

    const int nitems = NB*PP + NQ;
    const int count_blocks = (nitems + 255) / 256;
    // zero sums (knn atomics re-accumulate each launch) + pcnt..qcnt
    hipMemsetAsync((char*)d_ws + WS_SUMS_OFF, 0, WS_QSTART_OFF - WS_SUMS_OFF, stream);
    k_fused<<<1792 + count_blocks, 256, 0, stream>>>(fa, wswp, tex, wstex,
                                                     pts, coords, wspcnt, wsqcnt, use_t);
    k_scan2<<<1, 1024, 0, stream>>>(wspcnt, wspsta, wspcur, wsqcnt, wsqsta, wsqcur);
    k_scatter<<<count_blocks, 256, 0, stream>>>(pts, coords, wspcur, wsqcur,
                                                wspg, wspid, wsqid);
    k_knn_cell<<<NB*GC, 256, 0, stream>>>(coords, wspsta, wspcnt, wspg, wspid,
                                          wsqsta, wsqcnt, wsqid,
                                          out + OUT_DIST_OFF, wsidx, wssums64);
    k_main<<<NQ / 128, 1024, 0, stream>>>(coords, dirs, pts, tex, wstex, emb,
                                          wswp, pb1, pb2, fb1, fb2, fb3, db, rb1, rb2,
                                          wsidx, out + OUT_DIST_OFF, wssums64, out, use_t);
}

// Round 10
// 268.030 us; speedup vs baseline: 1.5382x; 1.5382x over previous
//
#include <hip/hip_runtime.h>
#include <float.h>
#include <math.h>

#define NB 2
#define MQ 16384
#define NQ (NB*MQ)          // 32768 queries
#define PP 5023
#define KNN 4
#define HPX 256
#define HWSZ (HPX*HPX)      // 65536
#define GD 12               // grid dim
#define GC (GD*GD*GD)       // 1728 cells
#define CAND_MAX 1024

// output layout (floats): densities[NQ], rgb[NQ*32], dist[NQ*4]
#define OUT_RGB_OFF  ((size_t)NQ)
#define OUT_DIST_OFF ((size_t)NQ + (size_t)NQ*32)

// workspace layout (bytes)
#define WS_SUMS_OFF   ((size_t)0x80000)
#define WS_PCNT_OFF   ((size_t)0x81000)
#define WS_PSTART_OFF ((size_t)0x85000)
#define WS_PCUR_OFF   ((size_t)0x89000)
#define WS_QCNT_OFF   ((size_t)0x8D000)
#define WS_QSTART_OFF ((size_t)0x91000)
#define WS_QCUR_OFF   ((size_t)0x95000)
#define WS_QID_OFF    ((size_t)0x99000)      // 32768*4 = 128 KB
#define WS_PG_OFF     ((size_t)0xC0000)      // 2*5023*16
#define WS_PID_OFF    ((size_t)0xF0000)      // 2*5023*4
#define WS_WP_OFF     ((size_t)0x100000)     // 29504 u32
#define WS_TEX_OFF    ((size_t)0x120000)     // 25.2 MB packed-f16 tex

// packed-weight sub-offsets (u32 units, in wp)
#define WP_PW1 0
#define WP_PW2 1920
#define WP_FW1 2944
#define WP_FW2 7040
#define WP_FW3 15232
#define WP_DW  23424
#define WP_RW1 23488
#define WP_RW2 28480

typedef __attribute__((ext_vector_type(2))) _Float16 half2v;

static __device__ __forceinline__ unsigned int pk2(float a, float b) {
    half2v h; h[0] = (_Float16)a; h[1] = (_Float16)b;   // RNE converts
    return __builtin_bit_cast(unsigned int, h);
}
static __device__ __forceinline__ float2 upk(unsigned int u) {
    half2v h = __builtin_bit_cast(half2v, u);
    return make_float2((float)h[0], (float)h[1]);
}
static __device__ __forceinline__ float dot2(unsigned int a, unsigned int b, float c) {
    return __builtin_amdgcn_fdot2(__builtin_bit_cast(half2v, a),
                                  __builtin_bit_cast(half2v, b), c, false);
}
static __device__ __forceinline__ int cell_of(float x) {
    int g = (int)(x * (float)GD);
    return (g < 0) ? 0 : ((g > GD-1) ? GD-1 : g);
}

// ------------------------------------------------------------------
// fused preprocessing: tex transpose (blocks 0..1535) | weight pack
// (blocks 1536..1791) | bucket count (blocks 1792..) — all independent.
struct FusedArgs {
    const float* src[8];
    int off[8]; int din[8]; int dout[8];
};
__global__ __launch_bounds__(256) void k_fused(
    FusedArgs a, unsigned int* __restrict__ wp,
    const float* __restrict__ tex, unsigned int* __restrict__ tex16,
    const float* __restrict__ pts, const float* __restrict__ coords,
    unsigned int* __restrict__ pcnt, unsigned int* __restrict__ qcnt,
    int use_t)
{
    const int b = blockIdx.x;
    const int tid = threadIdx.x;
    if (b < 1536) {
        // ---- texture transpose + f16 pack: [n3][32][HW] -> [n3][HW][16] u32
        if (!use_t) return;
        const int n3 = b >> 8;
        const int hw = ((b & 255) << 8) + tid;
        const float* s = tex + (size_t)n3 * 32 * HWSZ + hw;
        float v[32];
#pragma unroll
        for (int c = 0; c < 32; ++c) v[c] = s[(size_t)c * HWSZ];
        uint4* d = (uint4*)(tex16 + ((size_t)n3 * HWSZ + hw) * 16);
#pragma unroll
        for (int c = 0; c < 4; ++c)
            d[c] = make_uint4(pk2(v[8*c], v[8*c+1]), pk2(v[8*c+2], v[8*c+3]),
                              pk2(v[8*c+4], v[8*c+5]), pk2(v[8*c+6], v[8*c+7]));
    } else if (b < 1536 + 256) {
        // ---- weight pack
        const int b2 = b - 1536;
        const int mid = b2 >> 5;
        const int idx = (b2 & 31) * 256 + tid;
        const int DIN = a.din[mid], DOUT = a.dout[mid];
        const int din2 = (DIN + 1) >> 1;
        if (idx >= din2 * DOUT) return;
        const int i2 = idx / DOUT, j = idx - i2 * DOUT;
        const float* s = a.src[mid];
        const float lo = s[(2*i2) * DOUT + j];
        const float hi = (2*i2 + 1 < DIN) ? s[(2*i2 + 1) * DOUT + j] : 0.f;
        wp[a.off[mid] + idx] = pk2(lo, hi);
    } else {
        // ---- bucket count: points then queries
        const int i = (b - 1792) * 256 + tid;
        if (i < NB * PP) {
            const int n = (i >= PP) ? 1 : 0;
            const float px = pts[3*i], py = pts[3*i+1], pz = pts[3*i+2];
            const int c = (cell_of(pz)*GD + cell_of(py))*GD + cell_of(px);
            atomicAdd(&pcnt[n*GC + c], 1u);
        } else if (i - NB*PP < NQ) {
            const int q = i - NB*PP;
            const int n = q >> 14;
            const float cx = coords[3*q], cy = coords[3*q+1], cz = coords[3*q+2];
            const int c = (cell_of(cz)*GD + cell_of(cy))*GD + cell_of(cx);
            atomicAdd(&qcnt[n*GC + c], 1u);
        }
    }
}

// ------------------------------------------------------------------
// scan via wave shuffles: 8 barriers total (was ~120 with Hillis-Steele).
// R9-verified safe (no atomics, never in top-5).
__global__ __launch_bounds__(1024) void k_scan2(const unsigned int* __restrict__ pcnt,
                                                unsigned int* __restrict__ psta,
                                                unsigned int* __restrict__ pcur,
                                                const unsigned int* __restrict__ qcnt,
                                                unsigned int* __restrict__ qsta,
                                                unsigned int* __restrict__ qcur) {
    __shared__ unsigned int wsum[16];
    const int t = threadIdx.x;
    const int lane = t & 63, wv = t >> 6;
#pragma unroll 1
    for (int which = 0; which < 2; ++which) {
        const unsigned int* cnt = which ? qcnt : pcnt;
        unsigned int* start  = which ? qsta : psta;
        unsigned int* cursor = which ? qcur : pcur;
        const int stride = which ? MQ : PP;
#pragma unroll 1
        for (int n = 0; n < 2; ++n) {
            const unsigned int* c = cnt + n*GC;
            unsigned int a = (2*t   < GC) ? c[2*t]   : 0u;
            unsigned int b = (2*t+1 < GC) ? c[2*t+1] : 0u;
            unsigned int s = a + b;
            // intra-wave inclusive scan (no barriers)
            unsigned int inc = s;
#pragma unroll
            for (int off = 1; off < 64; off <<= 1) {
                unsigned int v = __shfl_up(inc, off);
                if (lane >= off) inc += v;
            }
            if (lane == 63) wsum[wv] = inc;
            __syncthreads();
            // wave 0 turns the 16 wave totals into exclusive bases
            if (wv == 0) {
                unsigned int x = (lane < 16) ? wsum[lane] : 0u;
                unsigned int xin = x;
#pragma unroll
                for (int off = 1; off < 16; off <<= 1) {
                    unsigned int v = __shfl_up(xin, off);
                    if (lane >= off) xin += v;
                }
                if (lane < 16) wsum[lane] = xin - x;   // exclusive wave base
            }
            __syncthreads();
            const unsigned int excl = wsum[wv] + (inc - s);
            const unsigned int base = n * stride;
            if (2*t < GC)   { start[n*GC + 2*t]   = base + excl;
                              cursor[n*GC + 2*t]  = base + excl; }
            if (2*t+1 < GC) { start[n*GC + 2*t+1] = base + excl + a;
                              cursor[n*GC + 2*t+1]= base + excl + a; }
            __syncthreads();   // wsum reused next round
        }
    }
}

__global__ __launch_bounds__(256) void k_scatter(const float* __restrict__ pts,
                                                 const float* __restrict__ coords,
                                                 unsigned int* __restrict__ pcur,
                                                 unsigned int* __restrict__ qcur,
                                                 float4* __restrict__ pg,
                                                 int* __restrict__ pid,
                                                 int* __restrict__ qid) {
    const int i = blockIdx.x * 256 + threadIdx.x;
    if (i < NB * PP) {
        const int n = (i >= PP) ? 1 : 0;
        const int local = i - n * PP;
        const float px = pts[3*i], py = pts[3*i+1], pz = pts[3*i+2];
        const int c = (cell_of(pz)*GD + cell_of(py))*GD + cell_of(px);
        const unsigned int pos = atomicAdd(&pcur[n*GC + c], 1u);
        pg[pos] = make_float4(px, py, pz, fmaf(px, px, fmaf(py, py, pz*pz)));
        pid[pos] = local;
    } else if (i - NB*PP < NQ) {
        const int q = i - NB*PP;
        const int n = q >> 14;
        const float cx = coords[3*q], cy = coords[3*q+1], cz = coords[3*q+2];
        const int c = (cell_of(cz)*GD + cell_of(cy))*GD + cell_of(cx);
        const unsigned int pos = atomicAdd(&qcur[n*GC + c], 1u);
        qid[pos] = q;
    }
}

// ------------------------------------------------------------------
// KNN (proven R13): ring<=2 candidates = <=25 x-contiguous pg ranges.
// NO sums fold — R5 (float CAS, +400us) and R9 (u64 hot atomics, +160us)
// both proved hot-spotted global atomics are poison; k_sums stays separate.
__global__ __launch_bounds__(256) void k_knn_cell(
    const float* __restrict__ coords,
    const unsigned int* __restrict__ pstart, const unsigned int* __restrict__ pcnt,
    const float4* __restrict__ pg, const int* __restrict__ pid,
    const unsigned int* __restrict__ qstart, const unsigned int* __restrict__ qcnt,
    const int* __restrict__ qid,
    float* __restrict__ odist, int* __restrict__ oidx)
{
    __shared__ float4 cand[CAND_MAX];        // 16 KB
    __shared__ int    cidx[CAND_MAX];        // 4 KB
    __shared__ unsigned int rs[25], ro[26];
    const int tid = threadIdx.x;
    const int bid = blockIdx.x;              // 2*GC
    const int n = bid / GC, c = bid % GC;
    const unsigned int qn = qcnt[n*GC + c];
    if (qn == 0) return;
    const int gz = c / (GD*GD), gy = (c / GD) % GD, gx = c % GD;

    const int x0 = max(gx-2,0), x1 = min(gx+2,GD-1);
    const int y0 = max(gy-2,0), y1 = min(gy+2,GD-1), ny = y1-y0+1;
    const int z0 = max(gz-2,0), z1 = min(gz+2,GD-1), nz = z1-z0+1;
    const int nrow = ny*nz;                  // <= 25

    __shared__ unsigned int rcnt[25];
    if (tid < nrow) {
        const int yy = y0 + tid % ny;
        const int zz = z0 + tid / ny;
        const int c0 = n*GC + (zz*GD + yy)*GD + x0;
        const int c1 = n*GC + (zz*GD + yy)*GD + x1;
        const unsigned int s = pstart[c0];
        rs[tid]   = s;
        rcnt[tid] = (pstart[c1] + pcnt[c1]) - s;   // x-contiguous range
    }
    __syncthreads();
    if (tid == 0) {
        unsigned int acc = 0; ro[0] = 0;
        for (int t = 0; t < nrow; ++t) { acc += rcnt[t]; ro[t+1] = acc; }
    }
    __syncthreads();
    const unsigned int total = ro[nrow];
    const bool ovf = (total > CAND_MAX);
    if (!ovf) {
        for (unsigned int i = tid; i < total; i += 256) {
            int lo = 0, hi = nrow;
            while (hi - lo > 1) { int mid = (lo + hi) >> 1; if (ro[mid] <= i) lo = mid; else hi = mid; }
            const unsigned int src = rs[lo] + (i - ro[lo]);
            cand[i] = pg[src];
            cidx[i] = pid[src];
        }
    }
    __syncthreads();

    const float w = 1.0f / (float)GD;
    const float thresh = 4.f * w * w * 0.999f;
    const int grp = tid >> 4, l16 = tid & 15;
    const unsigned int qs = qstart[n*GC + c];

#define INS4(d, i) { \
        bool L3 = ((d) < bd3) || ((d) == bd3 && (i) < bi3); \
        bool L2 = ((d) < bd2) || ((d) == bd2 && (i) < bi2); \
        bool L1 = ((d) < bd1) || ((d) == bd1 && (i) < bi1); \
        bool L0 = ((d) < bd0) || ((d) == bd0 && (i) < bi0); \
        bd3 = L3 ? (L2 ? bd2 : (d)) : bd3;  bi3 = L3 ? (L2 ? bi2 : (i)) : bi3; \
        bd2 = L2 ? (L1 ? bd1 : (d)) : bd2;  bi2 = L2 ? (L1 ? bi1 : (i)) : bi2; \
        bd1 = L1 ? (L0 ? bd0 : (d)) : bd1;  bi1 = L1 ? (L0 ? bi0 : (i)) : bi1; \
        bd0 = L0 ? (d) : bd0;               bi0 = L0 ? (i) : bi0; }

#define MERGE16() { \
        float bd[4] = { bd0, bd1, bd2, bd3 }; \
        int   bi[4] = { bi0, bi1, bi2, bi3 }; \
        for (int mask = 1; mask < 16; mask <<= 1) { \
            float od[4]; int oi[4]; \
            for (int j = 0; j < 4; ++j) { od[j] = __shfl_xor(bd[j], mask); \
                                          oi[j] = __shfl_xor(bi[j], mask); } \
            float e[4]; int ei[4]; \
            for (int j = 0; j < 4; ++j) { \
                float ad = bd[j], xd = od[3-j]; \
                int   ai = bi[j], xi = oi[3-j]; \
                bool ta = (ad < xd) || (ad == xd && ai < xi); \
                e[j] = ta ? ad : xd; ei[j] = ta ? ai : xi; \
            } \
            { bool sw = (e[2] < e[0]) || (e[2] == e[0] && ei[2] < ei[0]); \
              if (sw) { float td=e[0]; e[0]=e[2]; e[2]=td; int ti=ei[0]; ei[0]=ei[2]; ei[2]=ti; } } \
            { bool sw = (e[3] < e[1]) || (e[3] == e[1] && ei[3] < ei[1]); \
              if (sw) { float td=e[1]; e[1]=e[3]; e[3]=td; int ti=ei[1]; ei[1]=ei[3]; ei[3]=ti; } } \
            { bool sw = (e[1] < e[0]) || (e[1] == e[0] && ei[1] < ei[0]); \
              if (sw) { float td=e[0]; e[0]=e[1]; e[1]=td; int ti=ei[0]; ei[0]=ei[1]; ei[1]=ti; } } \
            { bool sw = (e[3] < e[2]) || (e[3] == e[2] && ei[3] < ei[2]); \
              if (sw) { float td=e[2]; e[2]=e[3]; e[3]=td; int ti=ei[2]; ei[2]=ei[3]; ei[3]=ti; } } \
            for (int j = 0; j < 4; ++j) { bd[j] = e[j]; bi[j] = ei[j]; } \
        } \
        bd0 = bd[0]; bd1 = bd[1]; bd2 = bd[2]; bd3 = bd[3]; \
        bi0 = bi[0]; bi1 = bi[1]; bi2 = bi[2]; bi3 = bi[3]; }

#pragma unroll 1
    for (unsigned int qb = 0; qb < qn; qb += 16) {
        const unsigned int qi = qb + grp;
        if (qi >= qn) continue;
        const int q = qid[qs + qi];
        const float cx = coords[3*q], cy = coords[3*q+1], cz = coords[3*q+2];
        const float ccq = fmaf(cx, cx, fmaf(cy, cy, cz*cz));

        float bd0 = FLT_MAX, bd1 = FLT_MAX, bd2 = FLT_MAX, bd3 = FLT_MAX;
        int   bi0 = 0x7fffffff, bi1 = 0x7fffffff, bi2 = 0x7fffffff, bi3 = 0x7fffffff;

        if (!ovf) {
#pragma unroll 1
            for (unsigned int j = l16; j < total; j += 16) {
                const float4 P = cand[j];
                const int i = cidx[j];
                const float dt = fmaf(cx, P.x, fmaf(cy, P.y, cz * P.z));
                const float d = fmaf(-2.0f, dt, ccq + P.w);
                INS4(d, i)
            }
            MERGE16()
        }
        if (ovf || !(bd3 < thresh)) {
            bd0 = bd1 = bd2 = bd3 = FLT_MAX;
            bi0 = bi1 = bi2 = bi3 = 0x7fffffff;
#pragma unroll 1
            for (int j = l16; j < PP; j += 16) {
                const float4 P = pg[n*PP + j];
                const int i = pid[n*PP + j];
                const float dt = fmaf(cx, P.x, fmaf(cy, P.y, cz * P.z));
                const float d = fmaf(-2.0f, dt, ccq + P.w);
                INS4(d, i)
            }
            MERGE16()
        }
        if (l16 == 0) {
            *(float4*)(odist + (size_t)q*4) = make_float4(bd0, bd1, bd2, bd3);
            *(int4*)(oidx + (size_t)q*4)    = make_int4(bi0, bi1, bi2, bi3);
        }
    }
#undef INS4
#undef MERGE16
}

// ------------------------------------------------------------------
__global__ __launch_bounds__(1024) void k_sums(const float* __restrict__ dist,
                                               float* __restrict__ sums) {
    const int b = blockIdx.x;            // n*4+k, 8 blocks
    const int n = b >> 2, k = b & 3;
    float s = 0.f;
    for (int m = threadIdx.x; m < MQ; m += 1024)
        s += 1.0f / dist[((size_t)n * MQ + m) * 4 + k];
    __shared__ float red[1024];
    red[threadIdx.x] = s;
    __syncthreads();
    for (int off = 512; off > 0; off >>= 1) {
        if (threadIdx.x < off) red[threadIdx.x] += red[threadIdx.x + off];
        __syncthreads();
    }
    if (threadIdx.x == 0) sums[b] = red[0];
}

// ------------------------------------------------------------------
static __device__ __forceinline__ float harm_val(int h, float rx, float ry, float rz) {
    if (h >= 27) return 0.f;
    float v;
    if (h < 24) {
        int base = (h < 12) ? h : (h - 12);
        float rv = (base >> 2) == 0 ? rx : ((base >> 2) == 1 ? ry : rz);
        float e = rv * (float)(1 << (base & 3));
        v = (h < 12) ? sinf(e) : cosf(e);
    } else {
        v = (h == 24) ? rx : ((h == 25) ? ry : rz);
    }
    return v;
}

#define SW 128   // S row stride in u32 (128 queries per block)

// gemv, 2 queries/lane: act b64 from S (pair 2*lane), weights b128 from W (LDS).
template<int DIN2, int DOUT, int TILE>
__device__ __forceinline__ void gemv2(const unsigned int* Xp, int lane,
                                      const unsigned int* Wl,
                                      const float* __restrict__ bias, int j0,
                                      float (&aa)[TILE], float (&ab)[TILE]) {
    static_assert(TILE % 4 == 0, "");
#pragma unroll
    for (int u = 0; u < TILE; ++u) { aa[u] = bias[j0 + u]; ab[u] = aa[u]; }
#pragma unroll
    for (int i2 = 0; i2 < DIN2; ++i2) {
        const uint2 xv = *(const uint2*)(Xp + i2 * SW + 2*lane);
        const uint4* wr = (const uint4*)(Wl + i2 * DOUT + j0);
#pragma unroll
        for (int t = 0; t < TILE/4; ++t) {
            const uint4 w4 = wr[t];
            aa[4*t+0] = dot2(xv.x, w4.x, aa[4*t+0]);  ab[4*t+0] = dot2(xv.y, w4.x, ab[4*t+0]);
            aa[4*t+1] = dot2(xv.x, w4.y, aa[4*t+1]);  ab[4*t+1] = dot2(xv.y, w4.y, ab[4*t+1]);
            aa[4*t+2] = dot2(xv.x, w4.z, aa[4*t+2]);  ab[4*t+2] = dot2(xv.y, w4.z, ab[4*t+2]);
            aa[4*t+3] = dot2(xv.x, w4.w, aa[4*t+3]);  ab[4*t+3] = dot2(xv.y, w4.w, ab[4*t+3]);
        }
    }
}

// ------------------------------------------------------------------
// main v24 == v22 k_main exactly (proven 92.4 µs, VALUBusy 46%, no spill).
__global__ __launch_bounds__(1024, 1) void k_main(
    const float* __restrict__ coords, const float* __restrict__ dirs,
    const float* __restrict__ pts, const float* __restrict__ tex_raw,
    const unsigned int* __restrict__ tex16, const float* __restrict__ emb,
    const unsigned int* __restrict__ wp,
    const float* __restrict__ pb1, const float* __restrict__ pb2,
    const float* __restrict__ fb1, const float* __restrict__ fb2,
    const float* __restrict__ fb3, const float* __restrict__ db,
    const float* __restrict__ rb1, const float* __restrict__ rb2,
    const int* __restrict__ idxbuf, const float* __restrict__ distbuf,
    const float* __restrict__ sums, float* __restrict__ out, int use_tex_t)
{
    __shared__ unsigned int S[128 * SW];               // 64 KB
    __shared__ __align__(16) unsigned int W[16384];    // 64 KB
    __shared__ float Rstg[128 * 33];                   // 16.5 KB
    const int tid  = threadIdx.x;
    const int lane = tid & 63;
    const int wv   = __builtin_amdgcn_readfirstlane(tid >> 6);   // 0..15
    const int q0   = blockIdx.x * 128;                 // 256 blocks
    const int n    = q0 >> 14;
    const int qa   = q0 + 2*lane;

#define STAGE(dstu4, srcoff, len) { \
        const uint4* s4_ = (const uint4*)(wp + (srcoff)); \
        for (int i_ = tid; i_ < (len)/4; i_ += 1024) ((uint4*)W)[(dstu4) + i_] = s4_[i_]; }

    // A-gather: neighbor features (emb, waves 0..7) + rel-harmonics
    // (waves 8..14) for neighbor kk -> S rows 64..93.
    auto gatherA = [&](int kk) {
#pragma unroll
        for (int s = 0; s < 2; ++s) {
            const int q = qa + s;
            const int id = idxbuf[(size_t)q*4 + kk];
            if (wv < 8) {
                const float4 e = *(const float4*)(emb + (size_t)id * 32 + wv*4);
                S[(64 + 2*wv    )*SW + 2*lane + s] = pk2(e.x, e.y);
                S[(64 + 2*wv + 1)*SW + 2*lane + s] = pk2(e.z, e.w);
            } else {
                const int w8 = wv - 8;
                if (w8 < 7) {
                    const float cx = coords[q*3+0], cy = coords[q*3+1], cz = coords[q*3+2];
                    const float nx = pts[((size_t)n*PP + id)*3 + 0];
                    const float ny = pts[((size_t)n*PP + id)*3 + 1];
                    const float nz = pts[((size_t)n*PP + id)*3 + 2];
                    float rx = cx - nx, ry = cy - ny, rz = cz - nz;
                    float nrm = sqrtf(fmaf(rx, rx, fmaf(ry, ry, rz*rz)));
                    float inv = 1.f / fmaxf(nrm, 1e-12f);
                    rx *= inv; ry *= inv; rz *= inv;
#pragma unroll
                    for (int t = 0; t < 2; ++t) {
                        const int pr = 2*w8 + t;          // 0..13
                        S[(80 + pr)*SW + 2*lane + s] =
                            pk2(harm_val(2*pr, rx, ry, rz), harm_val(2*pr + 1, rx, ry, rz));
                    }
                }
            }
        }
    };

    // ---------- tex sampling: wave = ch-pair g, lane = query pair ----------
    unsigned int tex_pack[2];
    {
        const int g = wv;
#pragma unroll
        for (int s = 0; s < 2; ++s) {
            const int q = qa + s;
            const float cx = coords[q*3+0], cy = coords[q*3+1], cz = coords[q*3+2];
            float a0 = 0.f, a1 = 0.f;
#pragma unroll
            for (int pl = 0; pl < 3; ++pl) {
                float gx = (pl == 2) ? cz : cx;
                float gy = (pl == 0) ? cy : ((pl == 1) ? cz : cx);
                float x = (gx + 1.f) * 128.f - 0.5f;
                float y = (gy + 1.f) * 128.f - 0.5f;
                float x0f = floorf(x), y0f = floorf(y);
                float wx1 = x - x0f, wy1 = y - y0f;
                float wx0 = 1.f - wx1, wy0 = 1.f - wy1;
                int x0 = (int)x0f, y0 = (int)y0f;
                int n3 = n * 3 + pl;
                int  xs[4] = { x0, x0+1, x0,   x0+1 };
                int  ys[4] = { y0, y0,   y0+1, y0+1 };
                float wt[4] = { wx0*wy0, wx1*wy0, wx0*wy1, wx1*wy1 };
#pragma unroll
                for (int c = 0; c < 4; ++c) {
                    int xi = xs[c], yi = ys[c];
                    if (xi >= 0 && xi < HPX && yi >= 0 && yi < HPX) {
                        float wgt = wt[c];
                        if (use_tex_t) {
                            const unsigned int v = tex16[
                                ((size_t)n3 * HWSZ + (size_t)yi * HPX + xi) * 16 + g];
                            const float2 f = upk(v);
                            a0 = fmaf(wgt, f.x, a0);
                            a1 = fmaf(wgt, f.y, a1);
                        } else {
                            size_t base = ((size_t)(n3 * 32 + g * 2)) * HWSZ + (size_t)yi * HPX + xi;
                            a0 = fmaf(wgt, tex_raw[base], a0);
                            a1 = fmaf(wgt, tex_raw[base + HWSZ], a1);
                        }
                    }
                }
            }
            tex_pack[s] = pk2(a0 * (1.f/3.f), a1 * (1.f/3.f));
        }
    }

    STAGE(0,    WP_PW1, 1920)        // pw1 @ u32 0
    STAGE(512,  WP_PW2, 1024)        // pw2 @ u32 2048
    STAGE(1024, WP_FW1, 4096)        // fw1 @ u32 4096
    gatherA(0);                      // A_0 hoisted before first barrier
    __syncthreads();

    STAGE(2048, WP_FW2, 8192)        // fw2 @ u32 8192, hidden under B_0's phase

    // ---------- neighbor loop: B_k; sync; {C_k + A_{k+1} | feat}; sync ----------
#pragma unroll 1
    for (int k = 0; k < KNN; ++k) {
        // B_k: p1 59->64 relu (W@0) -> h1 rows 96..127
        {
            float aa[4], ab[4];
            gemv2<30, 64, 4>(S + 64*SW, lane, W, pb1, wv * 4, aa, ab);
            S[(96 + 2*wv    )*SW + 2*lane + 0] = pk2(fmaxf(aa[0], 0.f), fmaxf(aa[1], 0.f));
            S[(96 + 2*wv    )*SW + 2*lane + 1] = pk2(fmaxf(ab[0], 0.f), fmaxf(ab[1], 0.f));
            S[(96 + 2*wv + 1)*SW + 2*lane + 0] = pk2(fmaxf(aa[2], 0.f), fmaxf(aa[3], 0.f));
            S[(96 + 2*wv + 1)*SW + 2*lane + 1] = pk2(fmaxf(ab[2], 0.f), fmaxf(ab[3], 0.f));
        }
        __syncthreads();
        // C_k: p2 64->32 (W@2048), wk-scaled -> row k*16 + wv
        {
            float aa[2], ab[2];
            aa[0] = pb2[wv*2 + 0]; aa[1] = pb2[wv*2 + 1];
            ab[0] = aa[0]; ab[1] = aa[1];
#pragma unroll
            for (int i2 = 0; i2 < 32; ++i2) {
                const uint2 xv = *(const uint2*)(S + (96 + i2)*SW + 2*lane);
                const unsigned int w0 = W[2048 + i2*32 + wv*2 + 0];
                const unsigned int w1 = W[2048 + i2*32 + wv*2 + 1];
                aa[0] = dot2(xv.x, w0, aa[0]);  ab[0] = dot2(xv.y, w0, ab[0]);
                aa[1] = dot2(xv.x, w1, aa[1]);  ab[1] = dot2(xv.y, w1, ab[1]);
            }
            const float da  = distbuf[(size_t)qa*4 + k];
            const float dbq = distbuf[(size_t)(qa+1)*4 + k];
            const float wka = (1.0f / da)  / sums[n*4 + k];
            const float wkb = (1.0f / dbq) / sums[n*4 + k];
            S[(k*16 + wv)*SW + 2*lane + 0] = pk2(wka * aa[0], wka * aa[1]);
            S[(k*16 + wv)*SW + 2*lane + 1] = pk2(wkb * ab[0], wkb * ab[1]);
        }
        if (k < KNN-1) {
            gatherA(k+1);              // rows 64..93, disjoint from C_k
        } else {
            // feat -> rows 64..95. pts-feat reads this thread's OWN C_k rows
            // (same row k*16+wv, same cols 2*lane) — same-thread LDS, no
            // barrier needed for the k=3 value written just above.
            S[(64 + wv)*SW + 2*lane + 0] = tex_pack[0];
            S[(64 + wv)*SW + 2*lane + 1] = tex_pack[1];
#pragma unroll
            for (int s = 0; s < 2; ++s) {
                float a = 0.f, b = 0.f;
#pragma unroll
                for (int kk = 0; kk < 4; ++kk) {
                    float2 v = upk(S[(kk*16 + wv)*SW + 2*lane + s]);
                    a += v.x; b += v.y;
                }
                S[(80 + wv)*SW + 2*lane + s] = pk2(a, b);
            }
        }
        __syncthreads();
    }

    // ---------- E: fw1 (W@4096) 64->128 relu, rows 64..95 -> rows 0..63 ----------
    {
        float aa[8], ab[8];
        gemv2<32, 128, 8>(S + 64*SW, lane, W + 4096, fb1, wv * 8, aa, ab);
#pragma unroll
        for (int u = 0; u < 4; ++u) {
            S[(4*wv + u)*SW + 2*lane + 0] = pk2(fmaxf(aa[2*u], 0.f), fmaxf(aa[2*u+1], 0.f));
            S[(4*wv + u)*SW + 2*lane + 1] = pk2(fmaxf(ab[2*u], 0.f), fmaxf(ab[2*u+1], 0.f));
        }
    }
    __syncthreads();
    // ---------- F: fw2 (W@8192) 128->128 relu, rows 0..63 -> 64..127;
    //             + stage fw3 -> W@0 (pw1/pw2/fw1 dead) ----------
    {
        float aa[8], ab[8];
        gemv2<64, 128, 8>(S, lane, W + 8192, fb2, wv * 8, aa, ab);
#pragma unroll
        for (int u = 0; u < 4; ++u) {
            S[(64 + 4*wv + u)*SW + 2*lane + 0] = pk2(fmaxf(aa[2*u], 0.f), fmaxf(aa[2*u+1], 0.f));
            S[(64 + 4*wv + u)*SW + 2*lane + 1] = pk2(fmaxf(ab[2*u], 0.f), fmaxf(ab[2*u+1], 0.f));
        }
    }
    STAGE(0, WP_FW3, 8192)
    __syncthreads();
    // ---------- G: fw3 (W@0) 128->128, rows 64..127 -> rows 0..63;
    //             + stage rw1/rw2/dw -> W@8192.. (fw2 dead) ----------
    {
        float aa[8], ab[8];
        gemv2<64, 128, 8>(S + 64*SW, lane, W, fb3, wv * 8, aa, ab);
#pragma unroll
        for (int u = 0; u < 4; ++u) {
            S[(4*wv + u)*SW + 2*lane + 0] = pk2(aa[2*u], aa[2*u+1]);
            S[(4*wv + u)*SW + 2*lane + 1] = pk2(ab[2*u], ab[2*u+1]);
        }
    }
    STAGE(2048, WP_RW1, 4992)        // rw1 @ u32 8192
    STAGE(3296, WP_RW2, 1024)        // rw2 @ u32 13184
    STAGE(3552, WP_DW, 64)           // dw  @ u32 14208
    __syncthreads();
    // ---------- ray-harm rows 64..77 (rows 64..127 dead after G) ----------
    if (wv < 14) {
#pragma unroll
        for (int s = 0; s < 2; ++s) {
            const int q = qa + s;
            float dx = dirs[q*3+0], dy = dirs[q*3+1], dz = dirs[q*3+2];
            float dn = sqrtf(fmaf(dx, dx, fmaf(dy, dy, dz*dz)));
            float inv = 1.f / fmaxf(dn, 1e-12f);
            dx *= inv; dy *= inv; dz *= inv;
            S[(64 + wv)*SW + 2*lane + s] = pk2(harm_val(2*wv, dx, dy, dz),
                                               harm_val(2*wv + 1, dx, dy, dz));
        }
    }
    __syncthreads();
    // ---------- I: rw1 (W@8192) 155->64 relu; rows 0..77 -> rows 78..109 ----------
    {
        float aa[4], ab[4];
        gemv2<78, 64, 4>(S, lane, W + 8192, rb1, wv * 4, aa, ab);
        S[(78 + 2*wv    )*SW + 2*lane + 0] = pk2(fmaxf(aa[0], 0.f), fmaxf(aa[1], 0.f));
        S[(78 + 2*wv    )*SW + 2*lane + 1] = pk2(fmaxf(ab[0], 0.f), fmaxf(ab[1], 0.f));
        S[(78 + 2*wv + 1)*SW + 2*lane + 0] = pk2(fmaxf(aa[2], 0.f), fmaxf(aa[3], 0.f));
        S[(78 + 2*wv + 1)*SW + 2*lane + 1] = pk2(fmaxf(ab[2], 0.f), fmaxf(ab[3], 0.f));
    }
    __syncthreads();
    // ---------- J: rw2 (W@13184) 64->32 + sigmoid -> Rstg; density (wave 15,
    //             dw @ W@14208) ----------
    {
        float aa[2], ab[2];
        aa[0] = rb2[wv*2 + 0]; aa[1] = rb2[wv*2 + 1];
        ab[0] = aa[0]; ab[1] = aa[1];
#pragma unroll
        for (int i2 = 0; i2 < 32; ++i2) {
            const uint2 xv = *(const uint2*)(S + (78 + i2)*SW + 2*lane);
            const unsigned int w0 = W[13184 + i2*32 + wv*2 + 0];
            const unsigned int w1 = W[13184 + i2*32 + wv*2 + 1];
            aa[0] = dot2(xv.x, w0, aa[0]);  ab[0] = dot2(xv.y, w0, ab[0]);
            aa[1] = dot2(xv.x, w1, aa[1]);  ab[1] = dot2(xv.y, w1, ab[1]);
        }
#pragma unroll
        for (int u = 0; u < 2; ++u) {
            const int j = wv*2 + u;
            float va = (u == 0) ? aa[0] : aa[1];
            float vb = (u == 0) ? ab[0] : ab[1];
            if (j < 3) {
                va = 1.002f * (1.f / (1.f + expf(-va))) - 0.001f;
                vb = 1.002f * (1.f / (1.f + expf(-vb))) - 0.001f;
            }
            Rstg[(2*lane    ) * 33 + j] = va;
            Rstg[(2*lane + 1) * 33 + j] = vb;
        }
        if (wv == 15) {
            float za = db[0], zb = db[0];
#pragma unroll 8
            for (int i2 = 0; i2 < 64; ++i2) {
                const uint2 xv = *(const uint2*)(S + i2*SW + 2*lane);
                const unsigned int wz = W[14208 + i2];
                za = dot2(xv.x, wz, za);
                zb = dot2(xv.y, wz, zb);
            }
#pragma unroll
            for (int s = 0; s < 2; ++s) {
                const int q = qa + s;
                const float z = (s == 0) ? za : zb;
                const float cx = coords[q*3+0], cy = coords[q*3+1], cz = coords[q*3+2];
                float selv = (cx > -1.f && cx < 1.f && cy > -1.f && cy < 1.f &&
                              cz > -1.f && cz < 1.f) ? 1.f : 0.f;
                float t10 = 10.f * z;
                float sp = (t10 > 20.f) ? t10 : log1pf(expf(t10));
                float raw = sp * 0.1f * selv;
                out[q] = 1.f - expf(-raw);
            }
        }
    }
    __syncthreads();
    // ---------- coalesced rgb writeback: 1 float4/thread ----------
    {
        const int cq = tid >> 3;             // 0..127
        const int j0 = (tid & 7) * 4;        // 0,4,...,28
        float4 v;
        v.x = Rstg[cq*33 + j0 + 0];
        v.y = Rstg[cq*33 + j0 + 1];
        v.z = Rstg[cq*33 + j0 + 2];
        v.w = Rstg[cq*33 + j0 + 3];
        *(float4*)(out + OUT_RGB_OFF + ((size_t)(q0 + cq))*32 + j0) = v;
    }
#undef STAGE
}

// ------------------------------------------------------------------
extern "C" void kernel_launch(void* const* d_in, const int* in_sizes, int n_in,
                              void* d_out, int out_size, void* d_ws, size_t ws_size,
                              hipStream_t stream) {
    (void)in_sizes; (void)n_in; (void)out_size;
    const float* coords = (const float*)d_in[0];
    const float* dirs   = (const float*)d_in[1];
    const float* pts    = (const float*)d_in[2];
    const float* tex    = (const float*)d_in[3];
    const float* emb    = (const float*)d_in[4];
    const float* pw1 = (const float*)d_in[5];  const float* pb1 = (const float*)d_in[6];
    const float* pw2 = (const float*)d_in[7];  const float* pb2 = (const float*)d_in[8];
    const float* fw1 = (const float*)d_in[9];  const float* fb1 = (const float*)d_in[10];
    const float* fw2 = (const float*)d_in[11]; const float* fb2 = (const float*)d_in[12];
    const float* fw3 = (const float*)d_in[13]; const float* fb3 = (const float*)d_in[14];
    const float* dw  = (const float*)d_in[15]; const float* db  = (const float*)d_in[16];
    const float* rw1 = (const float*)d_in[17]; const float* rb1 = (const float*)d_in[18];
    const float* rw2 = (const float*)d_in[19]; const float* rb2 = (const float*)d_in[20];

    float*        out     = (float*)d_out;
    int*          wsidx   = (int*)d_ws;
    float*        wssums  = (float*)((char*)d_ws + WS_SUMS_OFF);
    unsigned int* wspcnt  = (unsigned int*)((char*)d_ws + WS_PCNT_OFF);
    unsigned int* wspsta  = (unsigned int*)((char*)d_ws + WS_PSTART_OFF);
    unsigned int* wspcur  = (unsigned int*)((char*)d_ws + WS_PCUR_OFF);
    unsigned int* wsqcnt  = (unsigned int*)((char*)d_ws + WS_QCNT_OFF);
    unsigned int* wsqsta  = (unsigned int*)((char*)d_ws + WS_QSTART_OFF);
    unsigned int* wsqcur  = (unsigned int*)((char*)d_ws + WS_QCUR_OFF);
    int*          wsqid   = (int*)((char*)d_ws + WS_QID_OFF);
    float4*       wspg    = (float4*)((char*)d_ws + WS_PG_OFF);
    int*          wspid   = (int*)((char*)d_ws + WS_PID_OFF);
    unsigned int* wswp    = (unsigned int*)((char*)d_ws + WS_WP_OFF);
    unsigned int* wstex   = (unsigned int*)((char*)d_ws + WS_TEX_OFF);

    const size_t need_tex = WS_TEX_OFF + (size_t)6 * HWSZ * 16 * 4;
    const int use_t = (ws_size >= need_tex) ? 1 : 0;

    FusedArgs fa;
    fa.src[0] = pw1; fa.off[0] = WP_PW1; fa.din[0] = 59;  fa.dout[0] = 64;
    fa.src[1] = pw2; fa.off[1] = WP_PW2; fa.din[1] = 64;  fa.dout[1] = 32;
    fa.src[2] = fw1; fa.off[2] = WP_FW1; fa.din[2] = 64;  fa.dout[2] = 128;
    fa.src[3] = fw2; fa.off[3] = WP_FW2; fa.din[3] = 128; fa.dout[3] = 128;
    fa.src[4] = fw3; fa.off[4] = WP_FW3; fa.din[4] = 128; fa.dout[4] = 128;
    fa.src[5] = dw;  fa.off[5] = WP_DW;  fa.din[5] = 128; fa.dout[5] = 1;
    fa.src[6] = rw1; fa.off[6] = WP_RW1; fa.din[6] = 155; fa.dout[6] = 64;
    fa.src[7] = rw2; fa.off[7] = WP_RW2; fa.din[7] = 64;  fa.dout[7] = 32;

    const int nitems = NB*PP + NQ;
    const int count_blocks = (nitems + 255) / 256;
    hipMemsetAsync((char*)d_ws + WS_PCNT_OFF, 0, WS_QSTART_OFF - WS_PCNT_OFF, stream);
    k_fused<<<1792 + count_blocks, 256, 0, stream>>>(fa, wswp, tex, wstex,
                                                     pts, coords, wspcnt, wsqcnt, use_t);
    k_scan2<<<1, 1024, 0, stream>>>(wspcnt, wspsta, wspcur, wsqcnt, wsqsta, wsqcur);
    k_scatter<<<count_blocks, 256, 0, stream>>>(pts, coords, wspcur, wsqcur,
                                                wspg, wspid, wsqid);
    k_knn_cell<<<NB*GC, 256, 0, stream>>>(coords, wspsta, wspcnt, wspg, wspid,
                                          wsqsta, wsqcnt, wsqid,
                                          out + OUT_DIST_OFF, wsidx);
    k_sums<<<8, 1024, 0, stream>>>(out + OUT_DIST_OFF, wssums);
    k_main<<<NQ / 128, 1024, 0, stream>>>(coords, dirs, pts, tex, wstex, emb,
                                          wswp, pb1, pb2, fb1, fb2, fb3, db, rb1, rb2,
                                          wsidx, out + OUT_DIST_OFF, wssums, out, use_t);
}